// Round 2
// baseline (3322.557 us; speedup 1.0000x reference)
//
#include <hip/hip_runtime.h>
#include <math.h>

constexpr int NY_ = 320, NX_ = 320, NT_ = 160, SHOTS_ = 2, NSRC_ = 8, NREC_ = 96;
constexpr float DT_  = 4.0e-4f;
constexpr float C1_  = 9.0f / 8.0f;
constexpr float C2_  = -1.0f / 24.0f;
constexpr float IDH_ = 0.25f;           // 1/DH, exact
constexpr int NP_     = NY_ * NX_;
constexpr int NSTRIP_ = 40;             // 8-row strips per shot
constexpr int NBLK_   = SHOTS_ * NSTRIP_;
constexpr int NR_     = NT_ / 2;        // 80 rounds, 2 timesteps per round
// ws layout (float words):
//   stress grids [buf2][field3: syy,sxy,sxx][shot2][NP]
//   vms compact  [buf2][shot2][field6: vy,vx,msyyy,msxyy,msxyx,msxxx][strip40][4 rows(=owner rows 2..5)][NX]
//   receiver traces, flags
constexpr int VMS_OFF_  = 12 * NP_;
constexpr int VMS_SZ_   = 2 * SHOTS_ * 6 * NSTRIP_ * 4 * NX_;
constexpr int REC_OFF_  = VMS_OFF_ + VMS_SZ_;
constexpr int FLG_OFF_  = REC_OFF_ + SHOTS_ * NREC_ * NT_;
constexpr int WS_WORDS_ = FLG_OFF_ + 128;

// ---- coherent (IF-backed) access: relaxed agent-scope atomics ----
__device__ __forceinline__ float cld(const float* p) {
    return __hip_atomic_load(p, __ATOMIC_RELAXED, __HIP_MEMORY_SCOPE_AGENT);
}
__device__ __forceinline__ void cst(float* p, float v) {
    __hip_atomic_store(p, v, __ATOMIC_RELAXED, __HIP_MEMORY_SCOPE_AGENT);
}
__device__ __forceinline__ unsigned cldu(const unsigned* p) {
    return __hip_atomic_load(p, __ATOMIC_RELAXED, __HIP_MEMORY_SCOPE_AGENT);
}
__device__ __forceinline__ void cstu(unsigned* p, unsigned v) {
    __hip_atomic_store(p, v, __ATOMIC_RELAXED, __HIP_MEMORY_SCOPE_AGENT);
}

// guarded global halo load: out-of-grid rows read 0 (== masked border equivalence)
__device__ __forceinline__ float gldf(const float* p, int y, int c) {
    return ((unsigned)y < (unsigned)NY_) ? cld(p + y * NX_ + c) : 0.0f;
}
// guarded LDS x-tap: out-of-grid cols read 0
__device__ __forceinline__ float ltap(const float (*A)[NX_], int ly, int c) {
    return ((unsigned)c < (unsigned)NX_) ? A[ly][c] : 0.0f;
}
// register x-tap via wave shuffle (cells are 64-col interleaved, 5 groups/lane)
__device__ __forceinline__ float shtap(float cur, float adj, int lane, int dx) {
    int idx = (lane + dx) & 63;
    float a = __shfl(cur, idx, 64);
    float b = __shfl(adj, idx, 64);
    return ((unsigned)(lane + dx) < 64u) ? a : b;
}

// P2P neighbor sync (round-5-verified pattern)
__device__ __forceinline__ void pollNbr(const unsigned* f, int sbase, int j,
                                        unsigned tgt, int tid) {
    __syncthreads();
    if (tid < 64) {
        for (;;) {
            bool ok = true;
            if (tid == 0 && j > 0)                ok = cldu(&f[sbase + j - 1]) >= tgt;
            else if (tid == 1 && j < NSTRIP_ - 1) ok = cldu(&f[sbase + j + 1]) >= tgt;
            if (__all(ok)) break;
            __builtin_amdgcn_s_sleep(1);
        }
    }
    __syncthreads();
    asm volatile("" ::: "memory");
}

__device__ __forceinline__ float pml_by(int gy) {
    const double d0 = 3.0 * 1600.0 * log(1000.0) / (2.0 * 20.0 * 4.0);
    double py = 0.0;
    if (gy < 20)             { double u = (20.0 - gy) / 20.0;           py = u * u; }
    else if (gy >= NY_ - 20) { double u = (gy - (NY_ - 1 - 20)) / 20.0; py = u * u; }
    return (float)exp(-d0 * py * 4.0e-4);
}

__device__ __forceinline__ unsigned long long srcmask(const int* __restrict__ src_loc,
                                                      int s, int gy, int lane) {
    unsigned long long sm = 0ull;
    if ((unsigned)gy < (unsigned)NY_) {
        for (int js = 0; js < NSRC_; ++js) {
            int sy = src_loc[(s * NSRC_ + js) * 2 + 0];
            int sx = src_loc[(s * NSRC_ + js) * 2 + 1];
            if (sy == gy && (sx & 63) == lane) sm |= 1ull << (8 * (sx >> 6) + js);
        }
    }
    return sm;
}

// compact vms pointer: row gy maps to (owner strip, owner row-2)
__device__ __forceinline__ const float* vmsp(const float* ws, int buf, int s, int f, int gy) {
    int st = gy >> 3, ri = (gy & 7) - 2;   // transient rows always map to owner rows 2..5
    return ws + VMS_OFF_ + ((((buf * SHOTS_ + s) * 6 + f) * NSTRIP_ + st) * 4 + ri) * NX_;
}

// ---- one row's velocity + CPML update (used by P1 and P3; LDS idx base = y+7) ----
__device__ __forceinline__ void vupd(
    int lane, const float* __restrict__ ampsT,     // ampsS + t; src js amp at ampsT[js*NT_]
    float (&vyA)[5], float (&vxA)[5],
    float (&msyyyA)[5], float (&msxyyA)[5], float (&msxyxA)[5], float (&msxxxA)[5],
    const float (&sxxS)[5],
    const float (*SYY)[NX_], const float (*SXY)[NX_], int iY,
    float by, float bym1, const float (&bx)[5], const float (&bxm1)[5],
    const float (&bu)[5], float mr, const float (&mkc)[5],
    unsigned long long sm, bool doVy, bool doVx)
{
    #pragma unroll
    for (int k = 0; k < 5; ++k) {
        const int c = 64 * k + lane;
        float d;
        if (doVy) {
            // D-_y(syy)
            d = (C1_ * (SYY[iY][c] - SYY[iY - 1][c])
               + C2_ * (SYY[iY + 1][c] - SYY[iY - 2][c])) * IDH_;
            msyyyA[k] = by * msyyyA[k] + bym1 * d;
            float ay = d + msyyyA[k];
            // D+_x(sxy)
            d = (C1_ * (ltap(SXY, iY, c + 1) - SXY[iY][c])
               + C2_ * (ltap(SXY, iY, c + 2) - ltap(SXY, iY, c - 1))) * IDH_;
            msxyxA[k] = bx[k] * msxyxA[k] + bxm1[k] * d;
            ay = ay + d + msxyxA[k];
            vyA[k] = vyA[k] + DT_ * bu[k] * ay;
            unsigned m = (unsigned)(sm >> (8 * k)) & 0xFFu;
            if (m) {
                for (int js = 0; js < NSRC_; ++js)
                    if (m & (1u << js)) vyA[k] += DT_ * ampsT[js * NT_] * bu[k];
            }
            vyA[k] *= mr * mkc[k];
        }
        if (doVx) {
            const float sxxp = (k < 4) ? sxxS[k + 1] : 0.0f;
            const float sxxm = (k > 0) ? sxxS[k - 1] : 0.0f;
            // D-_x(sxx) via register shuffles
            d = (C1_ * (sxxS[k] - shtap(sxxS[k], sxxm, lane, -1))
               + C2_ * (shtap(sxxS[k], sxxp, lane, 1) - shtap(sxxS[k], sxxm, lane, -2))) * IDH_;
            msxxxA[k] = bx[k] * msxxxA[k] + bxm1[k] * d;
            float ax = d + msxxxA[k];
            // D+_y(sxy)
            d = (C1_ * (SXY[iY + 1][c] - SXY[iY][c])
               + C2_ * (SXY[iY + 2][c] - SXY[iY - 1][c])) * IDH_;
            msxyyA[k] = by * msxyyA[k] + bym1 * d;
            ax = ax + d + msxyyA[k];
            vxA[k] = vxA[k] + DT_ * bu[k] * ax;
            vxA[k] *= mr * mkc[k];
        }
    }
}

// ---- one row's stress + CPML update (used by D, P2, P4; Lvy idx y+5, Lvx idx y+6) ----
__device__ __forceinline__ void supd(
    int lane,
    float (&syyA)[5], float (&sxyA)[5], float (&sxxA)[5],
    float (&mvyyA)[5], float (&mvyxA)[5], float (&mvxyA)[5], float (&mvxxA)[5],
    const float (&vyS)[5], const float (&vxS)[5],
    const float (*VY)[NX_], int iy, const float (*VX)[NX_], int ix,
    float by, float bym1, const float (&bx)[5], const float (&bxm1)[5],
    const float (&la)[5], const float (&mu)[5], float mr, const float (&mkc)[5])
{
    #pragma unroll
    for (int k = 0; k < 5; ++k) {
        const int c = 64 * k + lane;
        float d, e1, e2, g;
        // D+_y(vy)
        d = (C1_ * (VY[iy + 1][c] - vyS[k]) + C2_ * (VY[iy + 2][c] - VY[iy - 1][c])) * IDH_;
        mvyyA[k] = by * mvyyA[k] + bym1 * d;
        e1 = d + mvyyA[k];
        // D-_x(vx)
        d = (C1_ * (vxS[k] - ltap(VX, ix, c - 1))
           + C2_ * (ltap(VX, ix, c + 1) - ltap(VX, ix, c - 2))) * IDH_;
        mvxxA[k] = bx[k] * mvxxA[k] + bxm1[k] * d;
        e2 = d + mvxxA[k];
        const float l2m = la[k] + 2.0f * mu[k];
        const float mk = mr * mkc[k];
        syyA[k] = (syyA[k] + DT_ * (l2m * e1 + la[k] * e2)) * mk;
        sxxA[k] = (sxxA[k] + DT_ * (l2m * e2 + la[k] * e1)) * mk;
        // D+_x(vy)
        d = (C1_ * (ltap(VY, iy, c + 1) - vyS[k])
           + C2_ * (ltap(VY, iy, c + 2) - ltap(VY, iy, c - 1))) * IDH_;
        mvyxA[k] = bx[k] * mvyxA[k] + bxm1[k] * d;
        g = d + mvyxA[k];
        // D-_y(vx)
        d = (C1_ * (vxS[k] - VX[ix - 1][c]) + C2_ * (VX[ix + 1][c] - VX[ix - 2][c])) * IDH_;
        mvxyA[k] = by * mvxyA[k] + bym1 * d;
        g = g + d + mvxyA[k];
        sxyA[k] = (sxyA[k] + DT_ * mu[k] * g) * mk;
    }
}

__global__ void init_kernel(float* __restrict__ ws) {
    for (int i = blockIdx.x * 256 + threadIdx.x; i < WS_WORDS_; i += gridDim.x * 256)
        ws[i] = 0.0f;
}

__global__ __launch_bounds__(512)
void elastic_kernel(const float* __restrict__ lamb, const float* __restrict__ mu,
                    const float* __restrict__ buoy, const float* __restrict__ amps,
                    const int* __restrict__ src_loc, const int* __restrict__ rec_loc,
                    float* __restrict__ out, float* __restrict__ ws)
{
    // LDS row maps (relative row y; owned rows are y=0..7):
    //   Lsyy/Lsxy: y -> y+7   (rows -7..14)  -- holds t, then t+1, then t+2 levels in phases
    //   Lvy:       y -> y+5   (rows -5..13)
    //   Lvx:       y -> y+6   (rows -6..12)
    __shared__ float Lsyy[22][NX_], Lsxy[22][NX_], Lvy[19][NX_], Lvx[19][NX_];

    const int tid  = threadIdx.x;
    const int lane = tid & 63;
    const int w    = tid >> 6;          // local owned row 0..7
    const int bid  = blockIdx.x;
    const int s    = bid / NSTRIP_;
    const int j    = bid % NSTRIP_;
    const int r0   = j * 8;
    const int gy   = r0 + w;

    unsigned* flg = (unsigned*)(ws + FLG_OFF_);
    const int sbase = s * NSTRIP_;
    float* recp = ws + REC_OFF_ + (s * NREC_ + tid) * NT_;   // valid only if tid<96
    const float* ampsS = amps + s * NSRC_ * NT_;

    // ---- slot rows ----
    // slotP (= slotS row): persistent-v ghost for edge waves, transient-v for middle waves;
    // the SAME row is each wave's persistent ghost-stress (sghost) row.
    const int yP_tab[8] = { -2, -1, -4, -3, 10, 11, 8, 9 };
    const int yP  = yP_tab[w];
    const int gP  = r0 + yP;
    const bool okP = (unsigned)gP < (unsigned)NY_;
    const bool midw = (w >= 2 && w <= 5);
    // slotT: extra transient v row (middle waves only); partial fields at the cone ends
    const int yT_tab[8] = { -100, -100, -6, -5, 13, 12, -100, -100 };
    const int yT  = yT_tab[w];
    const int gT  = r0 + yT;
    const bool okT = midw && ((unsigned)gT < (unsigned)NY_);
    const bool doVyT = (w == 3 || w == 4 || w == 5);   // vy computed on rows -5..13
    const bool doVxT = (w == 2 || w == 3 || w == 5);   // vx computed on rows -6..12

    // ---- per-cell loop invariants ----
    const float by   = pml_by(gy);
    const float bym1 = by - 1.0f;
    const float byP   = pml_by(gP);
    const float bym1P = byP - 1.0f;
    const float byT   = pml_by(gT);
    const float bym1T = byT - 1.0f;
    const float mrO = (gy >= 2 && gy < NY_ - 2) ? 1.0f : 0.0f;
    const float mrP = (gP >= 2 && gP < NY_ - 2) ? 1.0f : 0.0f;
    const float mrT = (gT >= 2 && gT < NY_ - 2) ? 1.0f : 0.0f;

    const double d0 = 3.0 * 1600.0 * log(1000.0) / (2.0 * 20.0 * 4.0);
    float bx[5], bxm1[5], mkc[5], buO[5], laO[5], muO[5], buP[5], laS[5], muS[5], buT[5];
    #pragma unroll
    for (int k = 0; k < 5; ++k) {
        int c = 64 * k + lane;
        double px = 0.0;
        if (c < 20)             { double u = (20.0 - c) / 20.0;           px = u * u; }
        else if (c >= NX_ - 20) { double u = (c - (NX_ - 1 - 20)) / 20.0; px = u * u; }
        bx[k] = (float)exp(-d0 * px * 4.0e-4);
        bxm1[k] = bx[k] - 1.0f;
        mkc[k] = (c >= 2 && c < NX_ - 2) ? 1.0f : 0.0f;
        buO[k] = buoy[gy * NX_ + c];
        laO[k] = lamb[gy * NX_ + c];
        muO[k] = mu[gy * NX_ + c];
        buP[k] = okP ? buoy[gP * NX_ + c] : 0.0f;
        laS[k] = okP ? lamb[gP * NX_ + c] : 0.0f;
        muS[k] = okP ? mu[gP * NX_ + c]   : 0.0f;
        buT[k] = okT ? buoy[gT * NX_ + c] : 0.0f;
    }

    const unsigned long long smO = srcmask(src_loc, s, gy, lane);
    const unsigned long long smP = okP ? srcmask(src_loc, s, gP, lane) : 0ull;
    const unsigned long long smT = okT ? srcmask(src_loc, s, gT, lane) : 0ull;

    // per-thread receiver (tid<96 handles receiver tid of this shot)
    bool myrec = false; int rl = 0;
    if (tid < NREC_) {
        int ry = rec_loc[(s * NREC_ + tid) * 2 + 0];
        int rx = rec_loc[(s * NREC_ + tid) * 2 + 1];
        if ((ry >> 3) == j) { myrec = true; rl = ((ry & 7) + 5) * NX_ + rx; }
    }

    // zero LDS
    for (int i = tid; i < 22 * NX_; i += 512) { ((float*)Lsyy)[i] = 0.f; ((float*)Lsxy)[i] = 0.f; }
    for (int i = tid; i < 19 * NX_; i += 512) { ((float*)Lvy)[i]  = 0.f; ((float*)Lvx)[i]  = 0.f; }

    // ---- register state ----
    float vy[5] = {}, vx[5] = {}, syy[5] = {}, sxy[5] = {}, sxx[5] = {};
    float msyyy[5] = {}, msxyy[5] = {}, msxyx[5] = {}, msxxx[5] = {};
    float mvyy[5] = {}, mvyx[5] = {}, mvxy[5] = {}, mvxx[5] = {};
    // slotP v-state: persistent for edge waves, re-imported each round for middle waves
    float vyP[5] = {}, vxP[5] = {};
    float msyyyP[5] = {}, msxyyP[5] = {}, msxyxP[5] = {}, msxxxP[5] = {};
    // slotS ghost-stress state: persistent for ALL waves (deferred-update scheme)
    float syyS[5] = {}, sxyS[5] = {}, sxxS[5] = {};
    float mvyyS[5] = {}, mvyxS[5] = {}, mvxyS[5] = {}, mvxxS[5] = {};
    // slotT: transient, re-imported each round
    float vyT[5] = {}, vxT[5] = {}, sxxT[5] = {};
    float msyyyT[5] = {}, msxyyT[5] = {}, msxyxT[5] = {}, msxxxT[5] = {};

    __syncthreads();

    for (int r = 0; r < NR_; ++r) {
        const int t0 = 2 * r;
        const int rb = r & 1, wb = rb ^ 1;   // ping-pong, reuse distance 2 rounds
        const float* rSyy = ws + ((rb * 3 + 0) * SHOTS_ + s) * NP_;
        const float* rSxy = ws + ((rb * 3 + 1) * SHOTS_ + s) * NP_;
        const float* rSxx = ws + ((rb * 3 + 2) * SHOTS_ + s) * NP_;
        float* wSyy = ws + ((wb * 3 + 0) * SHOTS_ + s) * NP_;
        float* wSxy = ws + ((wb * 3 + 1) * SHOTS_ + s) * NP_;
        float* wSxx = ws + ((wb * 3 + 2) * SHOTS_ + s) * NP_;

        // ============ single exchange point per 2 timesteps ============
        pollNbr(flg, sbase, j, (unsigned)r, tid);

        // ---- P0: imports ----
        if (midw) {
            if (okP) {   // transient v-state (6 fields) for slotP row
                const float* p0 = vmsp(ws, rb, s, 0, gP);
                const float* p1 = vmsp(ws, rb, s, 1, gP);
                const float* p2 = vmsp(ws, rb, s, 2, gP);
                const float* p3 = vmsp(ws, rb, s, 3, gP);
                const float* p4 = vmsp(ws, rb, s, 4, gP);
                const float* p5 = vmsp(ws, rb, s, 5, gP);
                #pragma unroll
                for (int k = 0; k < 5; ++k) {
                    int c = 64 * k + lane;
                    vyP[k]    = cld(p0 + c); vxP[k]    = cld(p1 + c);
                    msyyyP[k] = cld(p2 + c); msxyyP[k] = cld(p3 + c);
                    msxyxP[k] = cld(p4 + c); msxxxP[k] = cld(p5 + c);
                }
            }
            if (okT) {   // slotT partial fields
                if (doVyT) {
                    const float* p0 = vmsp(ws, rb, s, 0, gT);
                    const float* p2 = vmsp(ws, rb, s, 2, gT);
                    const float* p4 = vmsp(ws, rb, s, 4, gT);
                    #pragma unroll
                    for (int k = 0; k < 5; ++k) {
                        int c = 64 * k + lane;
                        vyT[k] = cld(p0 + c); msyyyT[k] = cld(p2 + c); msxyxT[k] = cld(p4 + c);
                    }
                }
                if (doVxT) {
                    const float* p1 = vmsp(ws, rb, s, 1, gT);
                    const float* p3 = vmsp(ws, rb, s, 3, gT);
                    const float* p5 = vmsp(ws, rb, s, 5, gT);
                    #pragma unroll
                    for (int k = 0; k < 5; ++k) {
                        int c = 64 * k + lane;
                        vxT[k] = cld(p1 + c); msxyyT[k] = cld(p3 + c); msxxxT[k] = cld(p5 + c);
                        sxxT[k] = cld(rSxx + gT * NX_ + c);
                    }
                }
            }
            // write transient v(t0) into LDS (needed by D taps and P1)
            if (okP) {
                #pragma unroll
                for (int k = 0; k < 5; ++k) {
                    int c = 64 * k + lane;
                    Lvy[yP + 5][c] = vyP[k]; Lvx[yP + 6][c] = vxP[k];
                }
            }
            if (okT) {
                #pragma unroll
                for (int k = 0; k < 5; ++k) {
                    int c = 64 * k + lane;
                    if (doVyT) Lvy[yT + 5][c] = vyT[k];
                    if (doVxT) Lvx[yT + 6][c] = vxT[k];
                }
            }
        } else {
            // edge waves: deep stress(t0) halo rows -> LDS
            // w0: syy{-7,-6,-5}  w1: sxy{-7,-6,-5}  w6: syy{12,13,14}  w7: sxy{12,13,14}
            const bool isyy = (w == 0 || w == 6);
            const int ybase = (w < 2) ? -7 : 12;
            const float* g = isyy ? rSyy : rSxy;
            #pragma unroll
            for (int i = 0; i < 3; ++i) {
                const int yr = ybase + i;
                #pragma unroll
                for (int k = 0; k < 5; ++k) {
                    int c = 64 * k + lane;
                    float v = gldf(g, r0 + yr, c);
                    if (isyy) Lsyy[yr + 7][c] = v; else Lsxy[yr + 7][c] = v;
                }
            }
        }
        __syncthreads();   // (A)

        // ---- D: deferred ghost final-stress (t0-1 -> t0) using v(t0) ----
        if (okP) {
            supd(lane, syyS, sxyS, sxxS, mvyyS, mvyxS, mvxyS, mvxxS,
                 vyP, vxP, Lvy, yP + 5, Lvx, yP + 6,
                 byP, bym1P, bx, bxm1, laS, muS, mrP, mkc);
            #pragma unroll
            for (int k = 0; k < 5; ++k) {
                int c = 64 * k + lane;
                Lsyy[yP + 7][c] = syyS[k]; Lsxy[yP + 7][c] = sxyS[k];
            }
        }
        __syncthreads();   // (B)

        // ---- P1: step-1 velocity (iteration t0) on rows -6..13 ----
        vupd(lane, ampsS + t0, vy, vx, msyyy, msxyy, msxyx, msxxx, sxx,
             Lsyy, Lsxy, w + 7, by, bym1, bx, bxm1, buO, mrO, mkc, smO, true, true);
        #pragma unroll
        for (int k = 0; k < 5; ++k) {
            int c = 64 * k + lane;
            Lvy[w + 5][c] = vy[k]; Lvx[w + 6][c] = vx[k];
        }
        if (okP) {
            vupd(lane, ampsS + t0, vyP, vxP, msyyyP, msxyyP, msxyxP, msxxxP, sxxS,
                 Lsyy, Lsxy, yP + 7, byP, bym1P, bx, bxm1, buP, mrP, mkc, smP, true, true);
            #pragma unroll
            for (int k = 0; k < 5; ++k) {
                int c = 64 * k + lane;
                Lvy[yP + 5][c] = vyP[k]; Lvx[yP + 6][c] = vxP[k];
            }
        }
        if (okT) {
            vupd(lane, ampsS + t0, vyT, vxT, msyyyT, msxyyT, msxyxT, msxxxT, sxxT,
                 Lsyy, Lsxy, yT + 7, byT, bym1T, bx, bxm1, buT, mrT, mkc, smT, doVyT, doVxT);
            #pragma unroll
            for (int k = 0; k < 5; ++k) {
                int c = 64 * k + lane;
                if (doVyT) Lvy[yT + 5][c] = vyT[k];
                if (doVxT) Lvx[yT + 6][c] = vxT[k];
            }
        }
        __syncthreads();   // (C)

        // ---- P2: record rec[t0]; mid stress (t0 -> t0+1) on rows -4..11 ----
        if (myrec) recp[t0] = ((const float*)Lvy)[rl];
        supd(lane, syy, sxy, sxx, mvyy, mvyx, mvxy, mvxx,
             vy, vx, Lvy, w + 5, Lvx, w + 6,
             by, bym1, bx, bxm1, laO, muO, mrO, mkc);
        #pragma unroll
        for (int k = 0; k < 5; ++k) {
            int c = 64 * k + lane;
            Lsyy[w + 7][c] = syy[k]; Lsxy[w + 7][c] = sxy[k];
        }
        if (okP) {
            supd(lane, syyS, sxyS, sxxS, mvyyS, mvyxS, mvxyS, mvxxS,
                 vyP, vxP, Lvy, yP + 5, Lvx, yP + 6,
                 byP, bym1P, bx, bxm1, laS, muS, mrP, mkc);
            #pragma unroll
            for (int k = 0; k < 5; ++k) {
                int c = 64 * k + lane;
                Lsyy[yP + 7][c] = syyS[k]; Lsxy[yP + 7][c] = sxyS[k];
            }
        }
        __syncthreads();   // (D)

        // ---- P3: step-2 velocity (iteration t0+1) on rows -2..9 ----
        vupd(lane, ampsS + t0 + 1, vy, vx, msyyy, msxyy, msxyx, msxxx, sxx,
             Lsyy, Lsxy, w + 7, by, bym1, bx, bxm1, buO, mrO, mkc, smO, true, true);
        #pragma unroll
        for (int k = 0; k < 5; ++k) {
            int c = 64 * k + lane;
            Lvy[w + 5][c] = vy[k]; Lvx[w + 6][c] = vx[k];
        }
        if (!midw && okP) {   // persistent ghosts -2,-1,8,9 get the second step too
            vupd(lane, ampsS + t0 + 1, vyP, vxP, msyyyP, msxyyP, msxyxP, msxxxP, sxxS,
                 Lsyy, Lsxy, yP + 7, byP, bym1P, bx, bxm1, buP, mrP, mkc, smP, true, true);
            #pragma unroll
            for (int k = 0; k < 5; ++k) {
                int c = 64 * k + lane;
                Lvy[yP + 5][c] = vyP[k]; Lvx[yP + 6][c] = vxP[k];
            }
        }
        // publish v(t0+2)+ms state of owned rows 2..5 (the neighbors' transient rows)
        if (midw) {
            float* q0 = (float*)vmsp(ws, wb, s, 0, gy);
            float* q1 = (float*)vmsp(ws, wb, s, 1, gy);
            float* q2 = (float*)vmsp(ws, wb, s, 2, gy);
            float* q3 = (float*)vmsp(ws, wb, s, 3, gy);
            float* q4 = (float*)vmsp(ws, wb, s, 4, gy);
            float* q5 = (float*)vmsp(ws, wb, s, 5, gy);
            #pragma unroll
            for (int k = 0; k < 5; ++k) {
                int c = 64 * k + lane;
                cst(q0 + c, vy[k]);    cst(q1 + c, vx[k]);
                cst(q2 + c, msyyy[k]); cst(q3 + c, msxyy[k]);
                cst(q4 + c, msxyx[k]); cst(q5 + c, msxxx[k]);
            }
        }
        __syncthreads();   // (E)

        // ---- P4: record rec[t0+1]; final stress (t0+1 -> t0+2) on owned rows; publish ----
        if (myrec) recp[t0 + 1] = ((const float*)Lvy)[rl];
        supd(lane, syy, sxy, sxx, mvyy, mvyx, mvxy, mvxx,
             vy, vx, Lvy, w + 5, Lvx, w + 6,
             by, bym1, bx, bxm1, laO, muO, mrO, mkc);
        #pragma unroll
        for (int k = 0; k < 5; ++k) {
            int c = 64 * k + lane;
            Lsyy[w + 7][c] = syy[k]; Lsxy[w + 7][c] = sxy[k];
            cst(&wSyy[gy * NX_ + c], syy[k]);
            cst(&wSxy[gy * NX_ + c], sxy[k]);
            cst(&wSxx[gy * NX_ + c], sxx[k]);
        }
        __syncthreads();   // (F) — compiler drains each wave's vmcnt before s_barrier
        if (tid == 0) {
            asm volatile("s_waitcnt vmcnt(0)" ::: "memory");
            cstu(&flg[sbase + j], (unsigned)(r + 1));
        }
    }

    // ---------- final output: out[s][r][t] = 0.5*(rec[t] + rec[t+1]) ----------
    if (myrec) {
        float* op = out + (s * NREC_ + tid) * (NT_ - 1);
        for (int t = 0; t < NT_ - 1; ++t) op[t] = 0.5f * (recp[t] + recp[t + 1]);
    }
}

extern "C" void kernel_launch(void* const* d_in, const int* in_sizes, int n_in,
                              void* d_out, int out_size, void* d_ws, size_t ws_size,
                              hipStream_t stream)
{
    const float* lamb = (const float*)d_in[0];
    const float* mu   = (const float*)d_in[1];
    const float* buoy = (const float*)d_in[2];
    const float* amps = (const float*)d_in[3];
    const int*   src  = (const int*)d_in[4];
    const int*   recl = (const int*)d_in[5];
    float* out = (float*)d_out;
    float* ws  = (float*)d_ws;

    init_kernel<<<dim3(512), dim3(256), 0, stream>>>(ws);
    elastic_kernel<<<dim3(NBLK_), dim3(512), 0, stream>>>(lamb, mu, buoy, amps, src, recl, out, ws);
}

// Round 3
// 2809.732 us; speedup vs baseline: 1.1825x; 1.1825x over previous
//
#include <hip/hip_runtime.h>
#include <math.h>

constexpr int NY_ = 320, NX_ = 320, NT_ = 160, SHOTS_ = 2, NSRC_ = 8, NREC_ = 96;
constexpr float DT_  = 4.0e-4f;
constexpr float C1_  = 9.0f / 8.0f;
constexpr float C2_  = -1.0f / 24.0f;
constexpr float IDH_ = 0.25f;           // 1/DH, exact
constexpr int NP_     = NY_ * NX_;
constexpr int NSTRIP_ = 40;             // 8-row strips per shot
constexpr int NBLK_   = SHOTS_ * NSTRIP_;
constexpr int NR_     = NT_ / 2;        // 80 rounds, 2 timesteps per round
// ws layout (float words):
//   stress grids [buf2][field3: syy,sxy,sxx][shot2][NP]
//   vms compact  [buf2][shot2][field6: vy,vx,msyyy,msxyy,msxyx,msxxx][strip40][4 rows(=owner rows 2..5)][NX]
//   receiver traces, flags
constexpr int VMS_OFF_  = 12 * NP_;
constexpr int VMS_SZ_   = 2 * SHOTS_ * 6 * NSTRIP_ * 4 * NX_;
constexpr int REC_OFF_  = VMS_OFF_ + VMS_SZ_;
constexpr int FLG_OFF_  = REC_OFF_ + SHOTS_ * NREC_ * NT_;
constexpr int WS_WORDS_ = FLG_OFF_ + 128;

// ---- coherent (IF-backed) access: relaxed agent-scope atomics ----
__device__ __forceinline__ float cld(const float* p) {
    return __hip_atomic_load(p, __ATOMIC_RELAXED, __HIP_MEMORY_SCOPE_AGENT);
}
__device__ __forceinline__ void cst(float* p, float v) {
    __hip_atomic_store(p, v, __ATOMIC_RELAXED, __HIP_MEMORY_SCOPE_AGENT);
}
__device__ __forceinline__ unsigned cldu(const unsigned* p) {
    return __hip_atomic_load(p, __ATOMIC_RELAXED, __HIP_MEMORY_SCOPE_AGENT);
}
__device__ __forceinline__ void cstu(unsigned* p, unsigned v) {
    __hip_atomic_store(p, v, __ATOMIC_RELAXED, __HIP_MEMORY_SCOPE_AGENT);
}

// guarded global halo load: out-of-grid rows read 0 (== masked border equivalence)
__device__ __forceinline__ float gldf(const float* p, int y, int c) {
    return ((unsigned)y < (unsigned)NY_) ? cld(p + y * NX_ + c) : 0.0f;
}
// guarded LDS x-tap: out-of-grid cols read 0
__device__ __forceinline__ float ltap(const float (*A)[NX_], int ly, int c) {
    return ((unsigned)c < (unsigned)NX_) ? A[ly][c] : 0.0f;
}
// register x-tap via wave shuffle (cells are 64-col interleaved, 5 groups/lane)
__device__ __forceinline__ float shtap(float cur, float adj, int lane, int dx) {
    int idx = (lane + dx) & 63;
    float a = __shfl(cur, idx, 64);
    float b = __shfl(adj, idx, 64);
    return ((unsigned)(lane + dx) < 64u) ? a : b;
}

// P2P neighbor sync (verified pattern)
__device__ __forceinline__ void pollNbr(const unsigned* f, int sbase, int j,
                                        unsigned tgt, int tid) {
    __syncthreads();
    if (tid < 64) {
        for (;;) {
            bool ok = true;
            if (tid == 0 && j > 0)                ok = cldu(&f[sbase + j - 1]) >= tgt;
            else if (tid == 1 && j < NSTRIP_ - 1) ok = cldu(&f[sbase + j + 1]) >= tgt;
            if (__all(ok)) break;
            __builtin_amdgcn_s_sleep(1);
        }
    }
    __syncthreads();
    asm volatile("" ::: "memory");
}

__device__ __forceinline__ float pml_by(int gy) {
    const double d0 = 3.0 * 1600.0 * log(1000.0) / (2.0 * 20.0 * 4.0);
    double py = 0.0;
    if (gy < 20)             { double u = (20.0 - gy) / 20.0;           py = u * u; }
    else if (gy >= NY_ - 20) { double u = (gy - (NY_ - 1 - 20)) / 20.0; py = u * u; }
    return (float)exp(-d0 * py * 4.0e-4);
}

__device__ __forceinline__ unsigned long long srcmask(const int* __restrict__ src_loc,
                                                      int s, int gy, int lane) {
    unsigned long long sm = 0ull;
    if ((unsigned)gy < (unsigned)NY_) {
        for (int js = 0; js < NSRC_; ++js) {
            int sy = src_loc[(s * NSRC_ + js) * 2 + 0];
            int sx = src_loc[(s * NSRC_ + js) * 2 + 1];
            if (sy == gy && (sx & 63) == lane) sm |= 1ull << (8 * (sx >> 6) + js);
        }
    }
    return sm;
}

// compact vms pointer: row gy maps to (owner strip, owner row-2)
__device__ __forceinline__ const float* vmsp(const float* ws, int buf, int s, int f, int gy) {
    int st = gy >> 3, ri = (gy & 7) - 2;   // transient rows always map to owner rows 2..5
    return ws + VMS_OFF_ + ((((buf * SHOTS_ + s) * 6 + f) * NSTRIP_ + st) * 4 + ri) * NX_;
}

// x-CPML static sparsity: memory vars for column groups k=1,2,3 (cols 64..255) are
// EXACTLY zero forever (bx=1, bx-1=0 outside x-PML) -> state arrays packed to [2]
// holding only k=0 and k=4. Bit-exact vs the full-width version.

// ---- one row's velocity + CPML update ----
__device__ __forceinline__ void vupd(
    int lane, const float* __restrict__ ampsT,     // ampsS + t; src js amp at ampsT[js*NT_]
    float (&vyA)[5], float (&vxA)[5],
    float (&msyyyA)[5], float (&msxyyA)[5], float (&msxyxA)[2], float (&msxxxA)[2],
    const float (&sxxS)[5],
    const float (*SYY)[NX_], const float (*SXY)[NX_], int iY,
    float by, float bym1, const float (&bx2)[2], const float (&bxm12)[2],
    const float (&bu)[5], float mr, const float (&mkc2)[2],
    unsigned long long sm, bool doVy, bool doVx)
{
    #pragma unroll
    for (int k = 0; k < 5; ++k) {
        const int c = 64 * k + lane;
        const bool px = (k == 0 || k == 4);   // x-PML possible only in edge groups
        const int xk = (k == 0) ? 0 : 1;
        const float mk = mr * (px ? mkc2[xk] : 1.0f);
        float d;
        if (doVy) {
            // D-_y(syy)
            d = (C1_ * (SYY[iY][c] - SYY[iY - 1][c])
               + C2_ * (SYY[iY + 1][c] - SYY[iY - 2][c])) * IDH_;
            msyyyA[k] = by * msyyyA[k] + bym1 * d;
            float ay = d + msyyyA[k];
            // D+_x(sxy)
            d = (C1_ * (ltap(SXY, iY, c + 1) - SXY[iY][c])
               + C2_ * (ltap(SXY, iY, c + 2) - ltap(SXY, iY, c - 1))) * IDH_;
            if (px) { msxyxA[xk] = bx2[xk] * msxyxA[xk] + bxm12[xk] * d; ay = ay + d + msxyxA[xk]; }
            else    { ay = ay + d; }
            vyA[k] = vyA[k] + DT_ * bu[k] * ay;
            unsigned m = (unsigned)(sm >> (8 * k)) & 0xFFu;
            if (m) {
                for (int js = 0; js < NSRC_; ++js)
                    if (m & (1u << js)) vyA[k] += DT_ * ampsT[js * NT_] * bu[k];
            }
            vyA[k] *= mk;
        }
        if (doVx) {
            const float sxxp = (k < 4) ? sxxS[k + 1] : 0.0f;
            const float sxxm = (k > 0) ? sxxS[k - 1] : 0.0f;
            // D-_x(sxx) via register shuffles
            d = (C1_ * (sxxS[k] - shtap(sxxS[k], sxxm, lane, -1))
               + C2_ * (shtap(sxxS[k], sxxp, lane, 1) - shtap(sxxS[k], sxxm, lane, -2))) * IDH_;
            float ax;
            if (px) { msxxxA[xk] = bx2[xk] * msxxxA[xk] + bxm12[xk] * d; ax = d + msxxxA[xk]; }
            else    { ax = d; }
            // D+_y(sxy)
            d = (C1_ * (SXY[iY + 1][c] - SXY[iY][c])
               + C2_ * (SXY[iY + 2][c] - SXY[iY - 1][c])) * IDH_;
            msxyyA[k] = by * msxyyA[k] + bym1 * d;
            ax = ax + d + msxyyA[k];
            vxA[k] = vxA[k] + DT_ * bu[k] * ax;
            vxA[k] *= mk;
        }
    }
}

// ---- one row's stress + CPML update ----
__device__ __forceinline__ void supd(
    int lane,
    float (&syyA)[5], float (&sxyA)[5], float (&sxxA)[5],
    float (&mvyyA)[5], float (&mvyxA)[2], float (&mvxyA)[5], float (&mvxxA)[2],
    const float (&vyS)[5], const float (&vxS)[5],
    const float (*VY)[NX_], int iy, const float (*VX)[NX_], int ix,
    float by, float bym1, const float (&bx2)[2], const float (&bxm12)[2],
    const float (&la)[5], const float (&mu)[5], float mr, const float (&mkc2)[2])
{
    #pragma unroll
    for (int k = 0; k < 5; ++k) {
        const int c = 64 * k + lane;
        const bool px = (k == 0 || k == 4);
        const int xk = (k == 0) ? 0 : 1;
        const float mk = mr * (px ? mkc2[xk] : 1.0f);
        float d, e1, e2, g;
        // D+_y(vy)
        d = (C1_ * (VY[iy + 1][c] - vyS[k]) + C2_ * (VY[iy + 2][c] - VY[iy - 1][c])) * IDH_;
        mvyyA[k] = by * mvyyA[k] + bym1 * d;
        e1 = d + mvyyA[k];
        // D-_x(vx)
        d = (C1_ * (vxS[k] - ltap(VX, ix, c - 1))
           + C2_ * (ltap(VX, ix, c + 1) - ltap(VX, ix, c - 2))) * IDH_;
        if (px) { mvxxA[xk] = bx2[xk] * mvxxA[xk] + bxm12[xk] * d; e2 = d + mvxxA[xk]; }
        else    { e2 = d; }
        const float l2m = la[k] + 2.0f * mu[k];
        syyA[k] = (syyA[k] + DT_ * (l2m * e1 + la[k] * e2)) * mk;
        sxxA[k] = (sxxA[k] + DT_ * (l2m * e2 + la[k] * e1)) * mk;
        // D+_x(vy)
        d = (C1_ * (ltap(VY, iy, c + 1) - vyS[k])
           + C2_ * (ltap(VY, iy, c + 2) - ltap(VY, iy, c - 1))) * IDH_;
        if (px) { mvyxA[xk] = bx2[xk] * mvyxA[xk] + bxm12[xk] * d; g = d + mvyxA[xk]; }
        else    { g = d; }
        // D-_y(vx)
        d = (C1_ * (vxS[k] - VX[ix - 1][c]) + C2_ * (VX[ix + 1][c] - VX[ix - 2][c])) * IDH_;
        mvxyA[k] = by * mvxyA[k] + bym1 * d;
        g = g + d + mvxyA[k];
        sxyA[k] = (sxyA[k] + DT_ * mu[k] * g) * mk;
    }
}

__global__ void init_kernel(float* __restrict__ ws) {
    for (int i = blockIdx.x * 256 + threadIdx.x; i < WS_WORDS_; i += gridDim.x * 256)
        ws[i] = 0.0f;
}

__global__ __launch_bounds__(512, 2)   // 2 waves/EU -> 256-VGPR cap, no scratch spills
void elastic_kernel(const float* __restrict__ lamb, const float* __restrict__ mu,
                    const float* __restrict__ buoy, const float* __restrict__ amps,
                    const int* __restrict__ src_loc, const int* __restrict__ rec_loc,
                    float* __restrict__ out, float* __restrict__ ws)
{
    // LDS row maps (relative row y; owned rows are y=0..7):
    //   Lsyy/Lsxy: y -> y+7   (rows -7..14)
    //   Lvy:       y -> y+5   (rows -5..13)
    //   Lvx:       y -> y+6   (rows -6..12)
    __shared__ float Lsyy[22][NX_], Lsxy[22][NX_], Lvy[19][NX_], Lvx[19][NX_];

    const int tid  = threadIdx.x;
    const int lane = tid & 63;
    const int w    = tid >> 6;          // local owned row 0..7
    const int bid  = blockIdx.x;
    const int s    = bid / NSTRIP_;
    const int j    = bid % NSTRIP_;
    const int r0   = j * 8;
    const int gy   = r0 + w;

    unsigned* flg = (unsigned*)(ws + FLG_OFF_);
    const int sbase = s * NSTRIP_;
    float* recp = ws + REC_OFF_ + (s * NREC_ + tid) * NT_;   // valid only if tid<96
    const float* ampsS = amps + s * NSRC_ * NT_;

    // ---- slot rows (arithmetic, no runtime-indexed local arrays -> no scratch) ----
    // slotP/slotS row: w 0..7 -> {-2,-1,-4,-3,10,11,8,9}
    const int yP = (w < 2) ? (w - 2) : (w < 4) ? (w - 6) : (w < 6) ? (w + 6) : (w + 2);
    const int gP  = r0 + yP;
    const bool okP = (unsigned)gP < (unsigned)NY_;
    const bool midw = (w >= 2 && w <= 5);
    // slotT row: w 2..5 -> {-6,-5,13,12}
    const int yT = (w == 2) ? -6 : (w == 3) ? -5 : (w == 4) ? 13 : (w == 5) ? 12 : -100;
    const int gT  = r0 + yT;
    const bool okT = midw && ((unsigned)gT < (unsigned)NY_);
    const bool doVyT = (w == 3 || w == 4 || w == 5);   // vy computed on rows -5..13
    const bool doVxT = (w == 2 || w == 3 || w == 5);   // vx computed on rows -6..12

    // ---- per-cell loop invariants ----
    const float by   = pml_by(gy);
    const float bym1 = by - 1.0f;
    const float byP   = pml_by(gP);
    const float bym1P = byP - 1.0f;
    const float byT   = pml_by(gT);
    const float bym1T = byT - 1.0f;
    const float mrO = (gy >= 2 && gy < NY_ - 2) ? 1.0f : 0.0f;
    const float mrP = (gP >= 2 && gP < NY_ - 2) ? 1.0f : 0.0f;
    const float mrT = (gT >= 2 && gT < NY_ - 2) ? 1.0f : 0.0f;

    const double d0 = 3.0 * 1600.0 * log(1000.0) / (2.0 * 20.0 * 4.0);
    float bx2[2], bxm12[2], mkc2[2];
    #pragma unroll
    for (int e = 0; e < 2; ++e) {
        int c = (e == 0) ? lane : 256 + lane;   // groups k=0 and k=4
        double pxd = 0.0;
        if (c < 20)             { double u = (20.0 - c) / 20.0;           pxd = u * u; }
        else if (c >= NX_ - 20) { double u = (c - (NX_ - 1 - 20)) / 20.0; pxd = u * u; }
        bx2[e] = (float)exp(-d0 * pxd * 4.0e-4);
        bxm12[e] = bx2[e] - 1.0f;
        mkc2[e] = (c >= 2 && c < NX_ - 2) ? 1.0f : 0.0f;
    }

    float buO[5], laO[5], muO[5], buP[5], laS[5], muS[5], buT[5];
    #pragma unroll
    for (int k = 0; k < 5; ++k) {
        int c = 64 * k + lane;
        buO[k] = buoy[gy * NX_ + c];
        laO[k] = lamb[gy * NX_ + c];
        muO[k] = mu[gy * NX_ + c];
        buP[k] = okP ? buoy[gP * NX_ + c] : 0.0f;
        laS[k] = okP ? lamb[gP * NX_ + c] : 0.0f;
        muS[k] = okP ? mu[gP * NX_ + c]   : 0.0f;
        buT[k] = okT ? buoy[gT * NX_ + c] : 0.0f;
    }

    const unsigned long long smO = srcmask(src_loc, s, gy, lane);
    const unsigned long long smP = okP ? srcmask(src_loc, s, gP, lane) : 0ull;
    const unsigned long long smT = okT ? srcmask(src_loc, s, gT, lane) : 0ull;

    // per-thread receiver (tid<96 handles receiver tid of this shot)
    bool myrec = false; int rl = 0;
    if (tid < NREC_) {
        int ry = rec_loc[(s * NREC_ + tid) * 2 + 0];
        int rx = rec_loc[(s * NREC_ + tid) * 2 + 1];
        if ((ry >> 3) == j) { myrec = true; rl = ((ry & 7) + 5) * NX_ + rx; }
    }

    // zero LDS
    for (int i = tid; i < 22 * NX_; i += 512) { ((float*)Lsyy)[i] = 0.f; ((float*)Lsxy)[i] = 0.f; }
    for (int i = tid; i < 19 * NX_; i += 512) { ((float*)Lvy)[i]  = 0.f; ((float*)Lvx)[i]  = 0.f; }

    // ---- register state (x-CPML packed to [2]) ----
    float vy[5] = {}, vx[5] = {}, syy[5] = {}, sxy[5] = {}, sxx[5] = {};
    float msyyy[5] = {}, msxyy[5] = {}, msxyx[2] = {}, msxxx[2] = {};
    float mvyy[5] = {}, mvyx[2] = {}, mvxy[5] = {}, mvxx[2] = {};
    // slotP v-state: persistent for edge waves, re-imported each round for middle waves
    float vyP[5] = {}, vxP[5] = {};
    float msyyyP[5] = {}, msxyyP[5] = {}, msxyxP[2] = {}, msxxxP[2] = {};
    // slotS ghost-stress state: persistent for ALL waves (deferred-update scheme)
    float syyS[5] = {}, sxyS[5] = {}, sxxS[5] = {};
    float mvyyS[5] = {}, mvyxS[2] = {}, mvxyS[5] = {}, mvxxS[2] = {};
    // slotT: transient, re-imported each round
    float vyT[5] = {}, vxT[5] = {}, sxxT[5] = {};
    float msyyyT[5] = {}, msxyyT[5] = {}, msxyxT[2] = {}, msxxxT[2] = {};

    __syncthreads();

    for (int r = 0; r < NR_; ++r) {
        const int t0 = 2 * r;
        const int rb = r & 1, wb = rb ^ 1;   // ping-pong, reuse distance 2 rounds
        const float* rSyy = ws + ((rb * 3 + 0) * SHOTS_ + s) * NP_;
        const float* rSxy = ws + ((rb * 3 + 1) * SHOTS_ + s) * NP_;
        const float* rSxx = ws + ((rb * 3 + 2) * SHOTS_ + s) * NP_;
        float* wSyy = ws + ((wb * 3 + 0) * SHOTS_ + s) * NP_;
        float* wSxy = ws + ((wb * 3 + 1) * SHOTS_ + s) * NP_;
        float* wSxx = ws + ((wb * 3 + 2) * SHOTS_ + s) * NP_;

        // ============ single exchange point per 2 timesteps ============
        pollNbr(flg, sbase, j, (unsigned)r, tid);

        // ---- P0: imports ----
        if (midw) {
            if (okP) {   // transient v-state for slotP row (fields 4,5 packed)
                const float* p0 = vmsp(ws, rb, s, 0, gP);
                const float* p1 = vmsp(ws, rb, s, 1, gP);
                const float* p2 = vmsp(ws, rb, s, 2, gP);
                const float* p3 = vmsp(ws, rb, s, 3, gP);
                const float* p4 = vmsp(ws, rb, s, 4, gP);
                const float* p5 = vmsp(ws, rb, s, 5, gP);
                #pragma unroll
                for (int k = 0; k < 5; ++k) {
                    int c = 64 * k + lane;
                    vyP[k]    = cld(p0 + c); vxP[k]    = cld(p1 + c);
                    msyyyP[k] = cld(p2 + c); msxyyP[k] = cld(p3 + c);
                }
                msxyxP[0] = cld(p4 + lane);       msxyxP[1] = cld(p4 + 256 + lane);
                msxxxP[0] = cld(p5 + lane);       msxxxP[1] = cld(p5 + 256 + lane);
            }
            if (okT) {   // slotT partial fields
                if (doVyT) {
                    const float* p0 = vmsp(ws, rb, s, 0, gT);
                    const float* p2 = vmsp(ws, rb, s, 2, gT);
                    const float* p4 = vmsp(ws, rb, s, 4, gT);
                    #pragma unroll
                    for (int k = 0; k < 5; ++k) {
                        int c = 64 * k + lane;
                        vyT[k] = cld(p0 + c); msyyyT[k] = cld(p2 + c);
                    }
                    msxyxT[0] = cld(p4 + lane);   msxyxT[1] = cld(p4 + 256 + lane);
                }
                if (doVxT) {
                    const float* p1 = vmsp(ws, rb, s, 1, gT);
                    const float* p3 = vmsp(ws, rb, s, 3, gT);
                    const float* p5 = vmsp(ws, rb, s, 5, gT);
                    #pragma unroll
                    for (int k = 0; k < 5; ++k) {
                        int c = 64 * k + lane;
                        vxT[k] = cld(p1 + c); msxyyT[k] = cld(p3 + c);
                        sxxT[k] = cld(rSxx + gT * NX_ + c);
                    }
                    msxxxT[0] = cld(p5 + lane);   msxxxT[1] = cld(p5 + 256 + lane);
                }
            }
            // write transient v(t0) into LDS (needed by D taps and P1)
            if (okP) {
                #pragma unroll
                for (int k = 0; k < 5; ++k) {
                    int c = 64 * k + lane;
                    Lvy[yP + 5][c] = vyP[k]; Lvx[yP + 6][c] = vxP[k];
                }
            }
            if (okT) {
                #pragma unroll
                for (int k = 0; k < 5; ++k) {
                    int c = 64 * k + lane;
                    if (doVyT) Lvy[yT + 5][c] = vyT[k];
                    if (doVxT) Lvx[yT + 6][c] = vxT[k];
                }
            }
        } else {
            // edge waves: deep stress(t0) halo rows -> LDS
            // w0: syy{-7,-6,-5}  w1: sxy{-7,-6,-5}  w6: syy{12,13,14}  w7: sxy{12,13,14}
            const bool isyy = (w == 0 || w == 6);
            const int ybase = (w < 2) ? -7 : 12;
            const float* g = isyy ? rSyy : rSxy;
            #pragma unroll
            for (int i = 0; i < 3; ++i) {
                const int yr = ybase + i;
                #pragma unroll
                for (int k = 0; k < 5; ++k) {
                    int c = 64 * k + lane;
                    float v = gldf(g, r0 + yr, c);
                    if (isyy) Lsyy[yr + 7][c] = v; else Lsxy[yr + 7][c] = v;
                }
            }
        }
        __syncthreads();   // (A)

        // ---- D: deferred ghost final-stress (t0-1 -> t0) using v(t0) ----
        if (okP) {
            supd(lane, syyS, sxyS, sxxS, mvyyS, mvyxS, mvxyS, mvxxS,
                 vyP, vxP, Lvy, yP + 5, Lvx, yP + 6,
                 byP, bym1P, bx2, bxm12, laS, muS, mrP, mkc2);
            #pragma unroll
            for (int k = 0; k < 5; ++k) {
                int c = 64 * k + lane;
                Lsyy[yP + 7][c] = syyS[k]; Lsxy[yP + 7][c] = sxyS[k];
            }
        }
        __syncthreads();   // (B)

        // ---- P1: step-1 velocity (iteration t0) on rows -6..13 ----
        vupd(lane, ampsS + t0, vy, vx, msyyy, msxyy, msxyx, msxxx, sxx,
             Lsyy, Lsxy, w + 7, by, bym1, bx2, bxm12, buO, mrO, mkc2, smO, true, true);
        #pragma unroll
        for (int k = 0; k < 5; ++k) {
            int c = 64 * k + lane;
            Lvy[w + 5][c] = vy[k]; Lvx[w + 6][c] = vx[k];
        }
        if (okP) {
            vupd(lane, ampsS + t0, vyP, vxP, msyyyP, msxyyP, msxyxP, msxxxP, sxxS,
                 Lsyy, Lsxy, yP + 7, byP, bym1P, bx2, bxm12, buP, mrP, mkc2, smP, true, true);
            #pragma unroll
            for (int k = 0; k < 5; ++k) {
                int c = 64 * k + lane;
                Lvy[yP + 5][c] = vyP[k]; Lvx[yP + 6][c] = vxP[k];
            }
        }
        if (okT) {
            vupd(lane, ampsS + t0, vyT, vxT, msyyyT, msxyyT, msxyxT, msxxxT, sxxT,
                 Lsyy, Lsxy, yT + 7, byT, bym1T, bx2, bxm12, buT, mrT, mkc2, smT, doVyT, doVxT);
            #pragma unroll
            for (int k = 0; k < 5; ++k) {
                int c = 64 * k + lane;
                if (doVyT) Lvy[yT + 5][c] = vyT[k];
                if (doVxT) Lvx[yT + 6][c] = vxT[k];
            }
        }
        __syncthreads();   // (C)

        // ---- P2: record rec[t0]; mid stress (t0 -> t0+1) on rows -4..11 ----
        if (myrec) recp[t0] = ((const float*)Lvy)[rl];
        supd(lane, syy, sxy, sxx, mvyy, mvyx, mvxy, mvxx,
             vy, vx, Lvy, w + 5, Lvx, w + 6,
             by, bym1, bx2, bxm12, laO, muO, mrO, mkc2);
        #pragma unroll
        for (int k = 0; k < 5; ++k) {
            int c = 64 * k + lane;
            Lsyy[w + 7][c] = syy[k]; Lsxy[w + 7][c] = sxy[k];
        }
        if (okP) {
            supd(lane, syyS, sxyS, sxxS, mvyyS, mvyxS, mvxyS, mvxxS,
                 vyP, vxP, Lvy, yP + 5, Lvx, yP + 6,
                 byP, bym1P, bx2, bxm12, laS, muS, mrP, mkc2);
            #pragma unroll
            for (int k = 0; k < 5; ++k) {
                int c = 64 * k + lane;
                Lsyy[yP + 7][c] = syyS[k]; Lsxy[yP + 7][c] = sxyS[k];
            }
        }
        __syncthreads();   // (D)

        // ---- P3: step-2 velocity (iteration t0+1) on rows -2..9 ----
        vupd(lane, ampsS + t0 + 1, vy, vx, msyyy, msxyy, msxyx, msxxx, sxx,
             Lsyy, Lsxy, w + 7, by, bym1, bx2, bxm12, buO, mrO, mkc2, smO, true, true);
        #pragma unroll
        for (int k = 0; k < 5; ++k) {
            int c = 64 * k + lane;
            Lvy[w + 5][c] = vy[k]; Lvx[w + 6][c] = vx[k];
        }
        if (!midw && okP) {   // persistent ghosts -2,-1,8,9 get the second step too
            vupd(lane, ampsS + t0 + 1, vyP, vxP, msyyyP, msxyyP, msxyxP, msxxxP, sxxS,
                 Lsyy, Lsxy, yP + 7, byP, bym1P, bx2, bxm12, buP, mrP, mkc2, smP, true, true);
            #pragma unroll
            for (int k = 0; k < 5; ++k) {
                int c = 64 * k + lane;
                Lvy[yP + 5][c] = vyP[k]; Lvx[yP + 6][c] = vxP[k];
            }
        }
        // publish v(t0+2)+ms state of owned rows 2..5 (the neighbors' transient rows)
        if (midw) {
            float* q0 = (float*)vmsp(ws, wb, s, 0, gy);
            float* q1 = (float*)vmsp(ws, wb, s, 1, gy);
            float* q2 = (float*)vmsp(ws, wb, s, 2, gy);
            float* q3 = (float*)vmsp(ws, wb, s, 3, gy);
            float* q4 = (float*)vmsp(ws, wb, s, 4, gy);
            float* q5 = (float*)vmsp(ws, wb, s, 5, gy);
            #pragma unroll
            for (int k = 0; k < 5; ++k) {
                int c = 64 * k + lane;
                cst(q0 + c, vy[k]);    cst(q1 + c, vx[k]);
                cst(q2 + c, msyyy[k]); cst(q3 + c, msxyy[k]);
            }
            cst(q4 + lane, msxyx[0]);       cst(q4 + 256 + lane, msxyx[1]);
            cst(q5 + lane, msxxx[0]);       cst(q5 + 256 + lane, msxxx[1]);
        }
        __syncthreads();   // (E)

        // ---- P4: record rec[t0+1]; final stress (t0+1 -> t0+2) on owned rows; publish ----
        if (myrec) recp[t0 + 1] = ((const float*)Lvy)[rl];
        supd(lane, syy, sxy, sxx, mvyy, mvyx, mvxy, mvxx,
             vy, vx, Lvy, w + 5, Lvx, w + 6,
             by, bym1, bx2, bxm12, laO, muO, mrO, mkc2);
        #pragma unroll
        for (int k = 0; k < 5; ++k) {
            int c = 64 * k + lane;
            Lsyy[w + 7][c] = syy[k]; Lsxy[w + 7][c] = sxy[k];
            cst(&wSyy[gy * NX_ + c], syy[k]);
            cst(&wSxy[gy * NX_ + c], sxy[k]);
            cst(&wSxx[gy * NX_ + c], sxx[k]);
        }
        __syncthreads();   // (F) — compiler drains each wave's vmcnt before s_barrier
        if (tid == 0) {
            asm volatile("s_waitcnt vmcnt(0)" ::: "memory");
            cstu(&flg[sbase + j], (unsigned)(r + 1));
        }
    }

    // ---------- final output: out[s][r][t] = 0.5*(rec[t] + rec[t+1]) ----------
    if (myrec) {
        float* op = out + (s * NREC_ + tid) * (NT_ - 1);
        for (int t = 0; t < NT_ - 1; ++t) op[t] = 0.5f * (recp[t] + recp[t + 1]);
    }
}

extern "C" void kernel_launch(void* const* d_in, const int* in_sizes, int n_in,
                              void* d_out, int out_size, void* d_ws, size_t ws_size,
                              hipStream_t stream)
{
    const float* lamb = (const float*)d_in[0];
    const float* mu   = (const float*)d_in[1];
    const float* buoy = (const float*)d_in[2];
    const float* amps = (const float*)d_in[3];
    const int*   src  = (const int*)d_in[4];
    const int*   recl = (const int*)d_in[5];
    float* out = (float*)d_out;
    float* ws  = (float*)d_ws;

    init_kernel<<<dim3(512), dim3(256), 0, stream>>>(ws);
    elastic_kernel<<<dim3(NBLK_), dim3(512), 0, stream>>>(lamb, mu, buoy, amps, src, recl, out, ws);
}

// Round 4
// 2411.314 us; speedup vs baseline: 1.3779x; 1.1652x over previous
//
#include <hip/hip_runtime.h>
#include <math.h>

constexpr int NY_ = 320, NX_ = 320, NT_ = 160, SHOTS_ = 2, NSRC_ = 8, NREC_ = 96;
constexpr float DT_  = 4.0e-4f;
constexpr float C1_  = 9.0f / 8.0f;
constexpr float C2_  = -1.0f / 24.0f;
constexpr float IDH_ = 0.25f;           // 1/DH, exact
constexpr int NP_     = NY_ * NX_;
constexpr int NSTRIP_ = 40;             // 8-row strips per shot
constexpr int NBLK_   = SHOTS_ * NSTRIP_;
constexpr int NR_     = NT_ / 2;        // 80 rounds, 2 timesteps per round
// ws layout (float words):
//   stress grids [buf2][field3: syy,sxy,sxx][shot2][NP]
//   vms compact  [buf2][shot2][field6: vy,vx,msyyy,msxyy,msxyx,msxxx][strip40][4 rows(=owner rows 2..5)][NX]
//   receiver traces, flags
constexpr int VMS_OFF_  = 12 * NP_;
constexpr int VMS_SZ_   = 2 * SHOTS_ * 6 * NSTRIP_ * 4 * NX_;
constexpr int REC_OFF_  = VMS_OFF_ + VMS_SZ_;
constexpr int FLG_OFF_  = REC_OFF_ + SHOTS_ * NREC_ * NT_;
constexpr int WS_WORDS_ = FLG_OFF_ + 128;

// ---- coherent (IF-backed) access: relaxed agent-scope atomics ----
__device__ __forceinline__ float cld(const float* p) {
    return __hip_atomic_load(p, __ATOMIC_RELAXED, __HIP_MEMORY_SCOPE_AGENT);
}
__device__ __forceinline__ void cst(float* p, float v) {
    __hip_atomic_store(p, v, __ATOMIC_RELAXED, __HIP_MEMORY_SCOPE_AGENT);
}
__device__ __forceinline__ unsigned cldu(const unsigned* p) {
    return __hip_atomic_load(p, __ATOMIC_RELAXED, __HIP_MEMORY_SCOPE_AGENT);
}
__device__ __forceinline__ void cstu(unsigned* p, unsigned v) {
    __hip_atomic_store(p, v, __ATOMIC_RELAXED, __HIP_MEMORY_SCOPE_AGENT);
}

// guarded global halo load: out-of-grid rows read 0 (== masked border equivalence)
__device__ __forceinline__ float gldf(const float* p, int y, int c) {
    return ((unsigned)y < (unsigned)NY_) ? cld(p + y * NX_ + c) : 0.0f;
}
// guarded LDS x-tap: out-of-grid cols read 0
__device__ __forceinline__ float ltap(const float (*A)[NX_], int ly, int c) {
    return ((unsigned)c < (unsigned)NX_) ? A[ly][c] : 0.0f;
}
// register x-tap via wave shuffle (cells are 64-col interleaved, 5 groups/lane)
__device__ __forceinline__ float shtap(float cur, float adj, int lane, int dx) {
    int idx = (lane + dx) & 63;
    float a = __shfl(cur, idx, 64);
    float b = __shfl(adj, idx, 64);
    return ((unsigned)(lane + dx) < 64u) ? a : b;
}

// P2P neighbor sync (verified pattern)
__device__ __forceinline__ void pollNbr(const unsigned* f, int sbase, int j,
                                        unsigned tgt, int tid) {
    __syncthreads();
    if (tid < 64) {
        for (;;) {
            bool ok = true;
            if (tid == 0 && j > 0)                ok = cldu(&f[sbase + j - 1]) >= tgt;
            else if (tid == 1 && j < NSTRIP_ - 1) ok = cldu(&f[sbase + j + 1]) >= tgt;
            if (__all(ok)) break;
            __builtin_amdgcn_s_sleep(1);
        }
    }
    __syncthreads();
    asm volatile("" ::: "memory");
}

__device__ __forceinline__ float pml_by(int gy) {
    const double d0 = 3.0 * 1600.0 * log(1000.0) / (2.0 * 20.0 * 4.0);
    double py = 0.0;
    if (gy < 20)             { double u = (20.0 - gy) / 20.0;           py = u * u; }
    else if (gy >= NY_ - 20) { double u = (gy - (NY_ - 1 - 20)) / 20.0; py = u * u; }
    return (float)exp(-d0 * py * 4.0e-4);
}

__device__ __forceinline__ unsigned long long srcmask(const int* __restrict__ src_loc,
                                                      int s, int gy, int lane) {
    unsigned long long sm = 0ull;
    if ((unsigned)gy < (unsigned)NY_) {
        for (int js = 0; js < NSRC_; ++js) {
            int sy = src_loc[(s * NSRC_ + js) * 2 + 0];
            int sx = src_loc[(s * NSRC_ + js) * 2 + 1];
            if (sy == gy && (sx & 63) == lane) sm |= 1ull << (8 * (sx >> 6) + js);
        }
    }
    return sm;
}

// compact vms pointer: row gy maps to (owner strip, owner row-2)
__device__ __forceinline__ const float* vmsp(const float* ws, int buf, int s, int f, int gy) {
    int st = gy >> 3, ri = (gy & 7) - 2;   // transient rows always map to owner rows 2..5
    return ws + VMS_OFF_ + ((((buf * SHOTS_ + s) * 6 + f) * NSTRIP_ + st) * 4 + ri) * NX_;
}

// x-CPML static sparsity: memory vars for column groups k=1,2,3 (cols 64..255) are
// EXACTLY zero forever (bx=1, bx-1=0 outside x-PML) -> state arrays packed to [2]
// holding only k=0 and k=4. Bit-exact vs the full-width version.
//
// Material params (lamb/mu/buoy) are NOT kept in registers: they are read-only,
// L2-resident regular loads; row base pointers are wave-uniform (SGPR), loads
// fold to saddr+lane-offset. This frees ~50 persistent VGPRs (round-3 spilled).

// ---- one row's velocity + CPML update ----
__device__ __forceinline__ void vupd(
    int lane, const float* __restrict__ ampsT,     // ampsS + t; src js amp at ampsT[js*NT_]
    float (&vyA)[5], float (&vxA)[5],
    float (&msyyyA)[5], float (&msxyyA)[5], float (&msxyxA)[2], float (&msxxxA)[2],
    const float (&sxxS)[5],
    const float (*SYY)[NX_], const float (*SXY)[NX_], int iY,
    float by, float bym1, const float (&bx2)[2], const float (&bxm12)[2],
    const float* __restrict__ buRow, float mr, const float (&mkc2)[2],
    unsigned long long sm, bool doVy, bool doVx)
{
    #pragma unroll
    for (int k = 0; k < 5; ++k) {
        const int c = 64 * k + lane;
        const bool px = (k == 0 || k == 4);   // x-PML possible only in edge groups
        const int xk = (k == 0) ? 0 : 1;
        const float mk = mr * (px ? mkc2[xk] : 1.0f);
        const float buk = buRow[c];
        float d;
        if (doVy) {
            // D-_y(syy)
            d = (C1_ * (SYY[iY][c] - SYY[iY - 1][c])
               + C2_ * (SYY[iY + 1][c] - SYY[iY - 2][c])) * IDH_;
            msyyyA[k] = by * msyyyA[k] + bym1 * d;
            float ay = d + msyyyA[k];
            // D+_x(sxy)
            d = (C1_ * (ltap(SXY, iY, c + 1) - SXY[iY][c])
               + C2_ * (ltap(SXY, iY, c + 2) - ltap(SXY, iY, c - 1))) * IDH_;
            if (px) { msxyxA[xk] = bx2[xk] * msxyxA[xk] + bxm12[xk] * d; ay = ay + d + msxyxA[xk]; }
            else    { ay = ay + d; }
            vyA[k] = vyA[k] + DT_ * buk * ay;
            unsigned m = (unsigned)(sm >> (8 * k)) & 0xFFu;
            if (m) {
                for (int js = 0; js < NSRC_; ++js)
                    if (m & (1u << js)) vyA[k] += DT_ * ampsT[js * NT_] * buk;
            }
            vyA[k] *= mk;
        }
        if (doVx) {
            const float sxxp = (k < 4) ? sxxS[k + 1] : 0.0f;
            const float sxxm = (k > 0) ? sxxS[k - 1] : 0.0f;
            // D-_x(sxx) via register shuffles
            d = (C1_ * (sxxS[k] - shtap(sxxS[k], sxxm, lane, -1))
               + C2_ * (shtap(sxxS[k], sxxp, lane, 1) - shtap(sxxS[k], sxxm, lane, -2))) * IDH_;
            float ax;
            if (px) { msxxxA[xk] = bx2[xk] * msxxxA[xk] + bxm12[xk] * d; ax = d + msxxxA[xk]; }
            else    { ax = d; }
            // D+_y(sxy)
            d = (C1_ * (SXY[iY + 1][c] - SXY[iY][c])
               + C2_ * (SXY[iY + 2][c] - SXY[iY - 1][c])) * IDH_;
            msxyyA[k] = by * msxyyA[k] + bym1 * d;
            ax = ax + d + msxyyA[k];
            vxA[k] = vxA[k] + DT_ * buk * ax;
            vxA[k] *= mk;
        }
    }
}

// ---- one row's stress + CPML update ----
__device__ __forceinline__ void supd(
    int lane,
    float (&syyA)[5], float (&sxyA)[5], float (&sxxA)[5],
    float (&mvyyA)[5], float (&mvyxA)[2], float (&mvxyA)[5], float (&mvxxA)[2],
    const float (&vyS)[5], const float (&vxS)[5],
    const float (*VY)[NX_], int iy, const float (*VX)[NX_], int ix,
    float by, float bym1, const float (&bx2)[2], const float (&bxm12)[2],
    const float* __restrict__ laRow, const float* __restrict__ muRow,
    float mr, const float (&mkc2)[2])
{
    #pragma unroll
    for (int k = 0; k < 5; ++k) {
        const int c = 64 * k + lane;
        const bool px = (k == 0 || k == 4);
        const int xk = (k == 0) ? 0 : 1;
        const float mk = mr * (px ? mkc2[xk] : 1.0f);
        const float lak = laRow[c];
        const float muk = muRow[c];
        float d, e1, e2, g;
        // D+_y(vy)
        d = (C1_ * (VY[iy + 1][c] - vyS[k]) + C2_ * (VY[iy + 2][c] - VY[iy - 1][c])) * IDH_;
        mvyyA[k] = by * mvyyA[k] + bym1 * d;
        e1 = d + mvyyA[k];
        // D-_x(vx)
        d = (C1_ * (vxS[k] - ltap(VX, ix, c - 1))
           + C2_ * (ltap(VX, ix, c + 1) - ltap(VX, ix, c - 2))) * IDH_;
        if (px) { mvxxA[xk] = bx2[xk] * mvxxA[xk] + bxm12[xk] * d; e2 = d + mvxxA[xk]; }
        else    { e2 = d; }
        const float l2m = lak + 2.0f * muk;
        syyA[k] = (syyA[k] + DT_ * (l2m * e1 + lak * e2)) * mk;
        sxxA[k] = (sxxA[k] + DT_ * (l2m * e2 + lak * e1)) * mk;
        // D+_x(vy)
        d = (C1_ * (ltap(VY, iy, c + 1) - vyS[k])
           + C2_ * (ltap(VY, iy, c + 2) - ltap(VY, iy, c - 1))) * IDH_;
        if (px) { mvyxA[xk] = bx2[xk] * mvyxA[xk] + bxm12[xk] * d; g = d + mvyxA[xk]; }
        else    { g = d; }
        // D-_y(vx)
        d = (C1_ * (vxS[k] - VX[ix - 1][c]) + C2_ * (VX[ix + 1][c] - VX[ix - 2][c])) * IDH_;
        mvxyA[k] = by * mvxyA[k] + bym1 * d;
        g = g + d + mvxyA[k];
        sxyA[k] = (sxyA[k] + DT_ * muk * g) * mk;
    }
}

__global__ void init_kernel(float* __restrict__ ws) {
    for (int i = blockIdx.x * 256 + threadIdx.x; i < WS_WORDS_; i += gridDim.x * 256)
        ws[i] = 0.0f;
}

// round-3 measurement: (512,2) produced a 128-VGPR cap (2nd arg acted as
// blocks-per-CU: 2 blk x 8 waves / 4 SIMD = 4 waves/EU). (512,1) gives the
// 256-VGPR cap under either interpretation (8-wave co-residency caps at 256).
__global__ __launch_bounds__(512, 1)
void elastic_kernel(const float* __restrict__ lamb, const float* __restrict__ mu,
                    const float* __restrict__ buoy, const float* __restrict__ amps,
                    const int* __restrict__ src_loc, const int* __restrict__ rec_loc,
                    float* __restrict__ out, float* __restrict__ ws)
{
    // LDS row maps (relative row y; owned rows are y=0..7):
    //   Lsyy/Lsxy: y -> y+7   (rows -7..14)
    //   Lvy:       y -> y+5   (rows -5..13)
    //   Lvx:       y -> y+6   (rows -6..12)
    __shared__ float Lsyy[22][NX_], Lsxy[22][NX_], Lvy[19][NX_], Lvx[19][NX_];

    const int tid  = threadIdx.x;
    const int lane = tid & 63;
    const int w    = tid >> 6;          // local owned row 0..7
    const int bid  = blockIdx.x;
    const int s    = bid / NSTRIP_;
    const int j    = bid % NSTRIP_;
    const int r0   = j * 8;
    const int gy   = r0 + w;

    unsigned* flg = (unsigned*)(ws + FLG_OFF_);
    const int sbase = s * NSTRIP_;
    float* recp = ws + REC_OFF_ + (s * NREC_ + tid) * NT_;   // valid only if tid<96
    const float* ampsS = amps + s * NSRC_ * NT_;

    // ---- slot rows (arithmetic, no runtime-indexed local arrays -> no scratch) ----
    // slotP/slotS row: w 0..7 -> {-2,-1,-4,-3,10,11,8,9}
    const int yP = (w < 2) ? (w - 2) : (w < 4) ? (w - 6) : (w < 6) ? (w + 6) : (w + 2);
    const int gP  = r0 + yP;
    const bool okP = (unsigned)gP < (unsigned)NY_;
    const bool midw = (w >= 2 && w <= 5);
    // slotT row: w 2..5 -> {-6,-5,13,12}
    const int yT = (w == 2) ? -6 : (w == 3) ? -5 : (w == 4) ? 13 : (w == 5) ? 12 : -100;
    const int gT  = r0 + yT;
    const bool okT = midw && ((unsigned)gT < (unsigned)NY_);
    const bool doVyT = (w == 3 || w == 4 || w == 5);   // vy computed on rows -5..13
    const bool doVxT = (w == 2 || w == 3 || w == 5);   // vx computed on rows -6..12

    // ---- material row base pointers (wave-uniform -> SGPRs; loads are L2-hits) ----
    const float* laO_p = lamb + gy * NX_;
    const float* muO_p = mu   + gy * NX_;
    const float* buO_p = buoy + gy * NX_;
    const float* laS_p = lamb + gP * NX_;   // deref only under okP
    const float* muS_p = mu   + gP * NX_;
    const float* buP_p = buoy + gP * NX_;
    const float* buT_p = buoy + gT * NX_;   // deref only under okT

    // ---- per-cell loop invariants ----
    const float by   = pml_by(gy);
    const float bym1 = by - 1.0f;
    const float byP   = pml_by(gP);
    const float bym1P = byP - 1.0f;
    const float byT   = pml_by(gT);
    const float bym1T = byT - 1.0f;
    const float mrO = (gy >= 2 && gy < NY_ - 2) ? 1.0f : 0.0f;
    const float mrP = (gP >= 2 && gP < NY_ - 2) ? 1.0f : 0.0f;
    const float mrT = (gT >= 2 && gT < NY_ - 2) ? 1.0f : 0.0f;

    const double d0 = 3.0 * 1600.0 * log(1000.0) / (2.0 * 20.0 * 4.0);
    float bx2[2], bxm12[2], mkc2[2];
    #pragma unroll
    for (int e = 0; e < 2; ++e) {
        int c = (e == 0) ? lane : 256 + lane;   // groups k=0 and k=4
        double pxd = 0.0;
        if (c < 20)             { double u = (20.0 - c) / 20.0;           pxd = u * u; }
        else if (c >= NX_ - 20) { double u = (c - (NX_ - 1 - 20)) / 20.0; pxd = u * u; }
        bx2[e] = (float)exp(-d0 * pxd * 4.0e-4);
        bxm12[e] = bx2[e] - 1.0f;
        mkc2[e] = (c >= 2 && c < NX_ - 2) ? 1.0f : 0.0f;
    }

    const unsigned long long smO = srcmask(src_loc, s, gy, lane);
    const unsigned long long smP = okP ? srcmask(src_loc, s, gP, lane) : 0ull;
    const unsigned long long smT = okT ? srcmask(src_loc, s, gT, lane) : 0ull;

    // per-thread receiver (tid<96 handles receiver tid of this shot)
    bool myrec = false; int rl = 0;
    if (tid < NREC_) {
        int ry = rec_loc[(s * NREC_ + tid) * 2 + 0];
        int rx = rec_loc[(s * NREC_ + tid) * 2 + 1];
        if ((ry >> 3) == j) { myrec = true; rl = ((ry & 7) + 5) * NX_ + rx; }
    }

    // zero LDS
    for (int i = tid; i < 22 * NX_; i += 512) { ((float*)Lsyy)[i] = 0.f; ((float*)Lsxy)[i] = 0.f; }
    for (int i = tid; i < 19 * NX_; i += 512) { ((float*)Lvy)[i]  = 0.f; ((float*)Lvx)[i]  = 0.f; }

    // ---- persistent register state (x-CPML packed to [2]) ----
    float vy[5] = {}, vx[5] = {}, syy[5] = {}, sxy[5] = {}, sxx[5] = {};
    float msyyy[5] = {}, msxyy[5] = {}, msxyx[2] = {}, msxxx[2] = {};
    float mvyy[5] = {}, mvyx[2] = {}, mvxy[5] = {}, mvxx[2] = {};
    // slotP v-state: persistent for edge waves, re-imported each round for middle waves
    float vyP[5] = {}, vxP[5] = {};
    float msyyyP[5] = {}, msxyyP[5] = {}, msxyxP[2] = {}, msxxxP[2] = {};
    // slotS ghost-stress state: persistent for ALL waves (deferred-update scheme)
    float syyS[5] = {}, sxyS[5] = {}, sxxS[5] = {};
    float mvyyS[5] = {}, mvyxS[2] = {}, mvxyS[5] = {}, mvxxS[2] = {};

    __syncthreads();

    for (int r = 0; r < NR_; ++r) {
        const int t0 = 2 * r;
        const int rb = r & 1, wb = rb ^ 1;   // ping-pong, reuse distance 2 rounds
        const float* rSyy = ws + ((rb * 3 + 0) * SHOTS_ + s) * NP_;
        const float* rSxy = ws + ((rb * 3 + 1) * SHOTS_ + s) * NP_;
        const float* rSxx = ws + ((rb * 3 + 2) * SHOTS_ + s) * NP_;
        float* wSyy = ws + ((wb * 3 + 0) * SHOTS_ + s) * NP_;
        float* wSxy = ws + ((wb * 3 + 1) * SHOTS_ + s) * NP_;
        float* wSxx = ws + ((wb * 3 + 2) * SHOTS_ + s) * NP_;

        // slotT state: liveness strictly P0..P1 within this round (in-loop scope)
        float vyT[5] = {}, vxT[5] = {}, sxxT[5] = {};
        float msyyyT[5] = {}, msxyyT[5] = {}, msxyxT[2] = {}, msxxxT[2] = {};

        // ============ single exchange point per 2 timesteps ============
        pollNbr(flg, sbase, j, (unsigned)r, tid);

        // ---- P0: imports ----
        if (midw) {
            if (okP) {   // transient v-state for slotP row (fields 4,5 packed)
                const float* p0 = vmsp(ws, rb, s, 0, gP);
                const float* p1 = vmsp(ws, rb, s, 1, gP);
                const float* p2 = vmsp(ws, rb, s, 2, gP);
                const float* p3 = vmsp(ws, rb, s, 3, gP);
                const float* p4 = vmsp(ws, rb, s, 4, gP);
                const float* p5 = vmsp(ws, rb, s, 5, gP);
                #pragma unroll
                for (int k = 0; k < 5; ++k) {
                    int c = 64 * k + lane;
                    vyP[k]    = cld(p0 + c); vxP[k]    = cld(p1 + c);
                    msyyyP[k] = cld(p2 + c); msxyyP[k] = cld(p3 + c);
                }
                msxyxP[0] = cld(p4 + lane);       msxyxP[1] = cld(p4 + 256 + lane);
                msxxxP[0] = cld(p5 + lane);       msxxxP[1] = cld(p5 + 256 + lane);
            }
            if (okT) {   // slotT partial fields
                if (doVyT) {
                    const float* p0 = vmsp(ws, rb, s, 0, gT);
                    const float* p2 = vmsp(ws, rb, s, 2, gT);
                    const float* p4 = vmsp(ws, rb, s, 4, gT);
                    #pragma unroll
                    for (int k = 0; k < 5; ++k) {
                        int c = 64 * k + lane;
                        vyT[k] = cld(p0 + c); msyyyT[k] = cld(p2 + c);
                    }
                    msxyxT[0] = cld(p4 + lane);   msxyxT[1] = cld(p4 + 256 + lane);
                }
                if (doVxT) {
                    const float* p1 = vmsp(ws, rb, s, 1, gT);
                    const float* p3 = vmsp(ws, rb, s, 3, gT);
                    const float* p5 = vmsp(ws, rb, s, 5, gT);
                    #pragma unroll
                    for (int k = 0; k < 5; ++k) {
                        int c = 64 * k + lane;
                        vxT[k] = cld(p1 + c); msxyyT[k] = cld(p3 + c);
                        sxxT[k] = cld(rSxx + gT * NX_ + c);
                    }
                    msxxxT[0] = cld(p5 + lane);   msxxxT[1] = cld(p5 + 256 + lane);
                }
            }
            // write transient v(t0) into LDS (needed by D taps and P1)
            if (okP) {
                #pragma unroll
                for (int k = 0; k < 5; ++k) {
                    int c = 64 * k + lane;
                    Lvy[yP + 5][c] = vyP[k]; Lvx[yP + 6][c] = vxP[k];
                }
            }
            if (okT) {
                #pragma unroll
                for (int k = 0; k < 5; ++k) {
                    int c = 64 * k + lane;
                    if (doVyT) Lvy[yT + 5][c] = vyT[k];
                    if (doVxT) Lvx[yT + 6][c] = vxT[k];
                }
            }
        } else {
            // edge waves: deep stress(t0) halo rows -> LDS
            // w0: syy{-7,-6,-5}  w1: sxy{-7,-6,-5}  w6: syy{12,13,14}  w7: sxy{12,13,14}
            const bool isyy = (w == 0 || w == 6);
            const int ybase = (w < 2) ? -7 : 12;
            const float* g = isyy ? rSyy : rSxy;
            #pragma unroll
            for (int i = 0; i < 3; ++i) {
                const int yr = ybase + i;
                #pragma unroll
                for (int k = 0; k < 5; ++k) {
                    int c = 64 * k + lane;
                    float v = gldf(g, r0 + yr, c);
                    if (isyy) Lsyy[yr + 7][c] = v; else Lsxy[yr + 7][c] = v;
                }
            }
        }
        __syncthreads();   // (A)

        // ---- D: deferred ghost final-stress (t0-1 -> t0) using v(t0) ----
        if (okP) {
            supd(lane, syyS, sxyS, sxxS, mvyyS, mvyxS, mvxyS, mvxxS,
                 vyP, vxP, Lvy, yP + 5, Lvx, yP + 6,
                 byP, bym1P, bx2, bxm12, laS_p, muS_p, mrP, mkc2);
            #pragma unroll
            for (int k = 0; k < 5; ++k) {
                int c = 64 * k + lane;
                Lsyy[yP + 7][c] = syyS[k]; Lsxy[yP + 7][c] = sxyS[k];
            }
        }
        __syncthreads();   // (B)

        // ---- P1: step-1 velocity (iteration t0) on rows -6..13 ----
        vupd(lane, ampsS + t0, vy, vx, msyyy, msxyy, msxyx, msxxx, sxx,
             Lsyy, Lsxy, w + 7, by, bym1, bx2, bxm12, buO_p, mrO, mkc2, smO, true, true);
        #pragma unroll
        for (int k = 0; k < 5; ++k) {
            int c = 64 * k + lane;
            Lvy[w + 5][c] = vy[k]; Lvx[w + 6][c] = vx[k];
        }
        if (okP) {
            vupd(lane, ampsS + t0, vyP, vxP, msyyyP, msxyyP, msxyxP, msxxxP, sxxS,
                 Lsyy, Lsxy, yP + 7, byP, bym1P, bx2, bxm12, buP_p, mrP, mkc2, smP, true, true);
            #pragma unroll
            for (int k = 0; k < 5; ++k) {
                int c = 64 * k + lane;
                Lvy[yP + 5][c] = vyP[k]; Lvx[yP + 6][c] = vxP[k];
            }
        }
        if (okT) {
            vupd(lane, ampsS + t0, vyT, vxT, msyyyT, msxyyT, msxyxT, msxxxT, sxxT,
                 Lsyy, Lsxy, yT + 7, byT, bym1T, bx2, bxm12, buT_p, mrT, mkc2, smT, doVyT, doVxT);
            #pragma unroll
            for (int k = 0; k < 5; ++k) {
                int c = 64 * k + lane;
                if (doVyT) Lvy[yT + 5][c] = vyT[k];
                if (doVxT) Lvx[yT + 6][c] = vxT[k];
            }
        }
        __syncthreads();   // (C)

        // ---- P2: record rec[t0]; mid stress (t0 -> t0+1) on rows -4..11 ----
        if (myrec) recp[t0] = ((const float*)Lvy)[rl];
        supd(lane, syy, sxy, sxx, mvyy, mvyx, mvxy, mvxx,
             vy, vx, Lvy, w + 5, Lvx, w + 6,
             by, bym1, bx2, bxm12, laO_p, muO_p, mrO, mkc2);
        #pragma unroll
        for (int k = 0; k < 5; ++k) {
            int c = 64 * k + lane;
            Lsyy[w + 7][c] = syy[k]; Lsxy[w + 7][c] = sxy[k];
        }
        if (okP) {
            supd(lane, syyS, sxyS, sxxS, mvyyS, mvyxS, mvxyS, mvxxS,
                 vyP, vxP, Lvy, yP + 5, Lvx, yP + 6,
                 byP, bym1P, bx2, bxm12, laS_p, muS_p, mrP, mkc2);
            #pragma unroll
            for (int k = 0; k < 5; ++k) {
                int c = 64 * k + lane;
                Lsyy[yP + 7][c] = syyS[k]; Lsxy[yP + 7][c] = sxyS[k];
            }
        }
        __syncthreads();   // (D)

        // ---- P3: step-2 velocity (iteration t0+1) on rows -2..9 ----
        vupd(lane, ampsS + t0 + 1, vy, vx, msyyy, msxyy, msxyx, msxxx, sxx,
             Lsyy, Lsxy, w + 7, by, bym1, bx2, bxm12, buO_p, mrO, mkc2, smO, true, true);
        #pragma unroll
        for (int k = 0; k < 5; ++k) {
            int c = 64 * k + lane;
            Lvy[w + 5][c] = vy[k]; Lvx[w + 6][c] = vx[k];
        }
        if (!midw && okP) {   // persistent ghosts -2,-1,8,9 get the second step too
            vupd(lane, ampsS + t0 + 1, vyP, vxP, msyyyP, msxyyP, msxyxP, msxxxP, sxxS,
                 Lsyy, Lsxy, yP + 7, byP, bym1P, bx2, bxm12, buP_p, mrP, mkc2, smP, true, true);
            #pragma unroll
            for (int k = 0; k < 5; ++k) {
                int c = 64 * k + lane;
                Lvy[yP + 5][c] = vyP[k]; Lvx[yP + 6][c] = vxP[k];
            }
        }
        // publish v(t0+2)+ms state of owned rows 2..5 (the neighbors' transient rows)
        if (midw) {
            float* q0 = (float*)vmsp(ws, wb, s, 0, gy);
            float* q1 = (float*)vmsp(ws, wb, s, 1, gy);
            float* q2 = (float*)vmsp(ws, wb, s, 2, gy);
            float* q3 = (float*)vmsp(ws, wb, s, 3, gy);
            float* q4 = (float*)vmsp(ws, wb, s, 4, gy);
            float* q5 = (float*)vmsp(ws, wb, s, 5, gy);
            #pragma unroll
            for (int k = 0; k < 5; ++k) {
                int c = 64 * k + lane;
                cst(q0 + c, vy[k]);    cst(q1 + c, vx[k]);
                cst(q2 + c, msyyy[k]); cst(q3 + c, msxyy[k]);
            }
            cst(q4 + lane, msxyx[0]);       cst(q4 + 256 + lane, msxyx[1]);
            cst(q5 + lane, msxxx[0]);       cst(q5 + 256 + lane, msxxx[1]);
        }
        __syncthreads();   // (E)

        // ---- P4: record rec[t0+1]; final stress (t0+1 -> t0+2) on owned rows; publish ----
        if (myrec) recp[t0 + 1] = ((const float*)Lvy)[rl];
        supd(lane, syy, sxy, sxx, mvyy, mvyx, mvxy, mvxx,
             vy, vx, Lvy, w + 5, Lvx, w + 6,
             by, bym1, bx2, bxm12, laO_p, muO_p, mrO, mkc2);
        #pragma unroll
        for (int k = 0; k < 5; ++k) {
            int c = 64 * k + lane;
            Lsyy[w + 7][c] = syy[k]; Lsxy[w + 7][c] = sxy[k];
            cst(&wSyy[gy * NX_ + c], syy[k]);
            cst(&wSxy[gy * NX_ + c], sxy[k]);
            cst(&wSxx[gy * NX_ + c], sxx[k]);
        }
        __syncthreads();   // (F) — compiler drains each wave's vmcnt before s_barrier
        if (tid == 0) {
            asm volatile("s_waitcnt vmcnt(0)" ::: "memory");
            cstu(&flg[sbase + j], (unsigned)(r + 1));
        }
    }

    // ---------- final output: out[s][r][t] = 0.5*(rec[t] + rec[t+1]) ----------
    if (myrec) {
        float* op = out + (s * NREC_ + tid) * (NT_ - 1);
        for (int t = 0; t < NT_ - 1; ++t) op[t] = 0.5f * (recp[t] + recp[t + 1]);
    }
}

extern "C" void kernel_launch(void* const* d_in, const int* in_sizes, int n_in,
                              void* d_out, int out_size, void* d_ws, size_t ws_size,
                              hipStream_t stream)
{
    const float* lamb = (const float*)d_in[0];
    const float* mu   = (const float*)d_in[1];
    const float* buoy = (const float*)d_in[2];
    const float* amps = (const float*)d_in[3];
    const int*   src  = (const int*)d_in[4];
    const int*   recl = (const int*)d_in[5];
    float* out = (float*)d_out;
    float* ws  = (float*)d_ws;

    init_kernel<<<dim3(512), dim3(256), 0, stream>>>(ws);
    elastic_kernel<<<dim3(NBLK_), dim3(512), 0, stream>>>(lamb, mu, buoy, amps, src, recl, out, ws);
}